// Round 15
// baseline (177.421 us; speedup 1.0000x reference)
//
#include <hip/hip_runtime.h>
#include <hip/hip_bf16.h>
#include <cstdint>

typedef __bf16 bf16_t;
typedef __attribute__((ext_vector_type(8))) __bf16 bf16x8;
typedef __attribute__((ext_vector_type(4))) __bf16 bf16x4;
typedef __attribute__((ext_vector_type(4))) float f32x4;

#define B_ 4
#define S_ 2048
#define E_ 1024
#define H_ 16
#define D_ 64

// Q pre-scale: (1/sqrt(D)) * log2(e) so softmax exp becomes a bare v_exp_f32 (2^x)
#define QSCALE 0.18033688011112042f

// ---------------- fused f32 -> bf16 conversion (single launch, 3 segments) --------
__global__ void cvt_all(const float* __restrict__ x, const float* __restrict__ wa,
                        const float* __restrict__ wo,
                        bf16_t* __restrict__ xb, bf16_t* __restrict__ wab,
                        bf16_t* __restrict__ wob) {
    constexpr int N1 = (B_ * S_ * E_) / 4;
    constexpr int N2 = (3 * E_ * E_) / 4;
    constexpr int N3 = (E_ * E_) / 4;
    int i = blockIdx.x * blockDim.x + threadIdx.x;
    int stride = gridDim.x * blockDim.x;
    for (; i < N1 + N2 + N3; i += stride) {
        const float* src; bf16_t* dst; int k;
        if (i < N1) { src = x; dst = xb; k = i; }
        else if (i < N1 + N2) { src = wa; dst = wab; k = i - N1; }
        else { src = wo; dst = wob; k = i - N1 - N2; }
        f32x4 v = reinterpret_cast<const f32x4*>(src)[k];
        bf16x4 o;
        o.x = (bf16_t)v.x; o.y = (bf16_t)v.y; o.z = (bf16_t)v.z; o.w = (bf16_t)v.w;
        reinterpret_cast<bf16x4*>(dst)[k] = o;
    }
}

// ---------------- async global->LDS helper ----------------
__device__ __forceinline__ void gload_lds16(const bf16_t* g, bf16_t* l) {
    __builtin_amdgcn_global_load_lds((const __attribute__((address_space(1))) void*)g,
                                     (__attribute__((address_space(3))) void*)l, 16, 0, 0);
}

__device__ __forceinline__ void wait_vm4() { asm volatile("s_waitcnt vmcnt(4)" ::: "memory"); }
__device__ __forceinline__ void wait_vm8() { asm volatile("s_waitcnt vmcnt(8)" ::: "memory"); }
__device__ __forceinline__ void wait_vm0() { asm volatile("s_waitcnt vmcnt(0)" ::: "memory"); }

// shared helpers for GEMM kernels
__device__ __forceinline__ int fragOffG(int row, int kc) {
    const int line = row >> 1;
    const int ch = ((row & 1) << 2) | kc;
    return line * 64 + ((ch ^ (line & 7)) << 3);
}

// ---------------- paired-tile deep-pipelined bf16 GEMM (QKV, r14 proven) ----------
__launch_bounds__(256, 3)
__global__ void gemm_qkv(const bf16_t* __restrict__ A, const bf16_t* __restrict__ Bm,
                         const float* __restrict__ bias,
                         bf16_t* __restrict__ Qg, bf16_t* __restrict__ Kg,
                         bf16_t* __restrict__ Vtg) {
    constexpr int K = 1024, BK = 32;
    constexpr int BM = 128, BN = 128;
    __shared__ __align__(16) bf16_t As[3][BM * BK];
    __shared__ __align__(16) bf16_t Bs[3][BN * BK];

    constexpr int NG = 12;
    const int xcd = blockIdx.x & 7;
    const int u = blockIdx.x >> 3;
    const int grp = 4 * NG;
    const int g = u / grp, r2 = u % grp;
    const int ntl = r2 >> 2, q = r2 & 3;
    const int mt0 = xcd * 8 + q;
    const int nt = g * NG + ntl;
    const int m0a = mt0 * BM, m0b = (mt0 + 4) * BM, n0 = nt * BN;

    const int t = threadIdx.x;
    const int lane = t & 63;
    const int wid = t >> 6;
    const int wr = wid >> 1, wc = wid & 1;
    const int lr = lane & 15, lg = lane >> 4;

    auto mkSrc = [&](const bf16_t* base, int c, int row0) {
        const int line = c >> 3, chg = (c & 7) ^ (line & 7);
        return base + (int64_t)(row0 + 2 * line + (chg >> 2)) * K + (chg & 3) * 8;
    };
    const bf16_t* aSrcA0 = mkSrc(A, t, m0a);
    const bf16_t* aSrcA1 = mkSrc(A, t + 256, m0a);
    const bf16_t* aSrcB0 = mkSrc(A, t, m0b);
    const bf16_t* aSrcB1 = mkSrc(A, t + 256, m0b);
    const bf16_t* bSrc0 = mkSrc(Bm, t, n0);
    const bf16_t* bSrc1 = mkSrc(Bm, t + 256, n0);

    auto stageT = [&](int v, int buf) {
        const int kt = v & 31;
        const bf16_t* a0 = (v < 32) ? aSrcA0 : aSrcB0;
        const bf16_t* a1 = (v < 32) ? aSrcA1 : aSrcB1;
        gload_lds16(a0 + kt * BK, &As[buf][t * 8]);
        gload_lds16(a1 + kt * BK, &As[buf][(t + 256) * 8]);
        gload_lds16(bSrc0 + kt * BK, &Bs[buf][t * 8]);
        gload_lds16(bSrc1 + kt * BK, &Bs[buf][(t + 256) * 8]);
    };

    f32x4 acc[4][4] = {};

    float bv[4];
#pragma unroll
    for (int j = 0; j < 4; ++j) bv[j] = bias[n0 + wc * 64 + j * 16 + lr];

    auto epi = [&](int m0) {
        const int which = n0 >> 10;
        const int h = (((n0 & 1023) + wc * 64) >> 6);
#pragma unroll
        for (int i = 0; i < 4; ++i) {
#pragma unroll
            for (int r = 0; r < 4; ++r) {
                const int m = m0 + wr * 64 + i * 16 + lg * 4 + r;
                const int b = m >> 11, si = m & (S_ - 1);
                if (which == 0) {
                    bf16_t* p = &Qg[(((int64_t)(b * H_ + h)) * S_ + si) * D_ + lr];
#pragma unroll
                    for (int j = 0; j < 4; ++j)
                        p[j * 16] = (bf16_t)((acc[i][j][r] + bv[j]) * QSCALE);
                } else if (which == 1) {
                    bf16_t* p = &Kg[(((int64_t)(b * H_ + h)) * S_ + si) * D_ + lr];
#pragma unroll
                    for (int j = 0; j < 4; ++j)
                        p[j * 16] = (bf16_t)(acc[i][j][r] + bv[j]);
                } else {
                    bf16_t* p = &Vtg[(((int64_t)(b * H_ + h)) * D_ + lr) * S_ + si];
#pragma unroll
                    for (int j = 0; j < 4; ++j)
                        p[(int64_t)(j * 16) * S_] = (bf16_t)(acc[i][j][r] + bv[j]);
                }
            }
        }
    };

    auto body = [&](int bufc) {
        bf16x8 bfr[4], afr[4];
#pragma unroll
        for (int j = 0; j < 4; ++j)
            bfr[j] = *(const bf16x8*)&Bs[bufc][fragOffG(wc * 64 + j * 16 + lr, lg)];
#pragma unroll
        for (int i = 0; i < 4; ++i)
            afr[i] = *(const bf16x8*)&As[bufc][fragOffG(wr * 64 + i * 16 + lr, lg)];
#pragma unroll
        for (int i = 0; i < 4; ++i)
#pragma unroll
            for (int j = 0; j < 4; ++j)
                acc[i][j] = __builtin_amdgcn_mfma_f32_16x16x32_bf16(afr[i], bfr[j], acc[i][j], 0, 0, 0);
    };

    stageT(0, 0);
    stageT(1, 1);

    int bufc = 0, bufs = 2;
    for (int v = 0; v < 32; ++v) {
        wait_vm4();
        __builtin_amdgcn_s_barrier();
        __builtin_amdgcn_sched_barrier(0);
        stageT(v + 2, bufs);            // crosses into tile b — no drain
        body(bufc);
        bufc = (bufc == 2) ? 0 : bufc + 1;
        bufs = (bufs == 2) ? 0 : bufs + 1;
    }
    epi(m0a);
#pragma unroll
    for (int i = 0; i < 4; ++i)
#pragma unroll
        for (int j = 0; j < 4; ++j)
            acc[i][j] = f32x4{0.f, 0.f, 0.f, 0.f};

    for (int v = 32; v < 64; ++v) {
        if (v < 63) wait_vm4(); else wait_vm0();
        __builtin_amdgcn_s_barrier();
        __builtin_amdgcn_sched_barrier(0);
        if (v + 2 < 64) stageT(v + 2, bufs);
        body(bufc);
        bufc = (bufc == 2) ? 0 : bufc + 1;
        bufs = (bufs == 2) ? 0 : bufs + 1;
    }
    epi(m0b);
}

// ---------------- barrier-free wave-private GEMM (output projection) --------------
// EXPERIMENT: AITER-style per-wave tiles. 512 blocks x 4 INDEPENDENT waves; each
// wave owns a 64x64 output tile with a private 2-buffer LDS ring (16 KiB/wave,
// 64 KiB/block -> 2 blocks/CU, grid = exactly 2/CU). Per-wave counted vmcnt(8)
// replaces all barriers — zero __syncthreads; waves never lockstep. lgkmcnt(0)
// before re-staging a ring slot guarantees the frag reads retired. Out = f32.
__launch_bounds__(256, 2)
__global__ void gemm_proj(const bf16_t* __restrict__ A, const bf16_t* __restrict__ Bm,
                          const float* __restrict__ bias, float* __restrict__ Outf) {
    constexpr int K = 1024, BK = 32, NKT = K / BK;
    constexpr int N = 1024;
    // [wave][buf][A(2048)|B(2048)] bf16 = 4 * 2 * 4096 * 2B = 64 KiB
    __shared__ __align__(16) bf16_t WS[4 * 2 * 4096];

    const int t = threadIdx.x;
    const int lane = t & 63;
    const int wid = t >> 6;
    const int lr = lane & 15, lg = lane >> 4;

    // XCD map: 512 blocks; xcd owns a 16-mt band (A 2MB) + full B (2MB) = 4MB L2.
    const int xcd = blockIdx.x & 7;
    const int u = blockIdx.x >> 3;          // 0..63
    const int nt = u & 15;
    const int mtq = xcd * 4 + (u >> 4);     // quad index 0..31
    const int mt = mtq * 4 + wid;           // per-wave tile row (0..127)
    const int m0 = mt * 64, n0 = nt * 64;

    bf16_t* Aw = &WS[wid * 8192];           // [buf][2048]
    bf16_t* Bw = &WS[wid * 8192 + 2048];    // interleave A/B within buf region

    auto mkSrc = [&](const bf16_t* base, int c, int row0) {
        const int line = c >> 3, chg = (c & 7) ^ (line & 7);
        return base + (int64_t)(row0 + 2 * line + (chg >> 2)) * K + (chg & 3) * 8;
    };
    const bf16_t* aS[4];
    const bf16_t* bS[4];
#pragma unroll
    for (int i = 0; i < 4; ++i) {
        aS[i] = mkSrc(A, lane + i * 64, m0);
        bS[i] = mkSrc(Bm, lane + i * 64, n0);
    }

    // stage one K-tile into wave-private buf (8 gloads/lane)
    auto stageT = [&](int kt, int buf) {
        bf16_t* a = Aw + buf * 4096;
        bf16_t* b = Bw + buf * 4096;
#pragma unroll
        for (int i = 0; i < 4; ++i) {
            gload_lds16(aS[i] + kt * BK, &a[(lane + i * 64) * 8]);
            gload_lds16(bS[i] + kt * BK, &b[(lane + i * 64) * 8]);
        }
    };

    f32x4 acc[4][4] = {};

    stageT(0, 0);
    stageT(1, 1);

    for (int kt = 0; kt < NKT; ++kt) {
        if (kt < NKT - 1) wait_vm8(); else wait_vm0();   // per-wave gate, no barrier

        const int bufc = kt & 1;
        const bf16_t* a = Aw + bufc * 4096;
        const bf16_t* b = Bw + bufc * 4096;

        bf16x8 afr[4], bfr[4];
#pragma unroll
        for (int i = 0; i < 4; ++i) {
            afr[i] = *(const bf16x8*)&a[fragOffG(i * 16 + lr, lg)];
            bfr[i] = *(const bf16x8*)&b[fragOffG(i * 16 + lr, lg)];
        }
        // frag reads must retire before this ring slot is overwritten
        asm volatile("s_waitcnt lgkmcnt(0)" ::: "memory");
        __builtin_amdgcn_sched_barrier(0);
        if (kt + 2 < NKT) stageT(kt + 2, bufc);

#pragma unroll
        for (int i = 0; i < 4; ++i)
#pragma unroll
            for (int j = 0; j < 4; ++j)
                acc[i][j] = __builtin_amdgcn_mfma_f32_16x16x32_bf16(afr[i], bfr[j], acc[i][j], 0, 0, 0);
    }

    float bv[4];
#pragma unroll
    for (int j = 0; j < 4; ++j) bv[j] = bias[n0 + j * 16 + lr];
#pragma unroll
    for (int i = 0; i < 4; ++i) {
#pragma unroll
        for (int r = 0; r < 4; ++r) {
            const int m = m0 + i * 16 + lg * 4 + r;
            float* p = &Outf[(int64_t)m * N + n0 + lr];
#pragma unroll
            for (int j = 0; j < 4; ++j)
                p[j * 16] = acc[i][j][r] + bv[j];
        }
    }
}

// ---------------- flash-style causal attention, work-balanced pairs (r11 proven) --
__launch_bounds__(256, 4)
__global__ void attn_causal(const bf16_t* __restrict__ Qg, const bf16_t* __restrict__ Kg,
                            const bf16_t* __restrict__ Vtg, bf16_t* __restrict__ Og) {
    __shared__ __align__(16) bf16_t Ks[2][64 * 64];   // 16 KiB
    __shared__ __align__(16) bf16_t Vs[2][64 * 64];   // 16 KiB
    __shared__ __align__(16) bf16_t P_lds[4][16 * 64]; // 8 KiB, swizzled

    const int bid = blockIdx.x;
    const int xcd = bid & 7, j = bid >> 3;
    const int bh = (j >> 4) * 8 + xcd;
    const int i = j & 15;
    const int qtA = i, qtB = 31 - i;

    const int t = threadIdx.x, lane = t & 63, w = t >> 6;
    const int lr = lane & 15, lg = lane >> 4;
    const int q0A = qtA * 64 + w * 16;
    const int q0B = qtB * 64 + w * 16;

    const bf16_t* Qb = Qg + (int64_t)bh * S_ * D_;
    const bf16_t* Kb = Kg + (int64_t)bh * S_ * D_;
    const bf16_t* Vb = Vtg + (int64_t)bh * D_ * S_;

    const int srow = t >> 3;
    const int scol_sw = (t & 7) ^ (srow & 7);

    auto stageK = [&](int buf, int kv0) {
        const bf16_t* base = Kb + (kv0 + srow) * D_ + scol_sw * 8;
        gload_lds16(base, &Ks[buf][t * 8]);
        gload_lds16(base + 32 * D_, &Ks[buf][t * 8 + 2048]);
    };
    auto stageV = [&](int buf, int kv0) {
        const bf16_t* base = Vb + srow * S_ + kv0 + scol_sw * 8;
        gload_lds16(base, &Vs[buf][t * 8]);
        gload_lds16(base + 32 * S_, &Vs[buf][t * 8 + 2048]);
    };

    auto psw = [](int row, int col) {
        return row * 64 + ((((col >> 3) ^ (row & 7)) << 3) | (col & 7));
    };

    bf16x8 qfA[2], qfB[2];
#pragma unroll
    for (int kk = 0; kk < 2; ++kk) {
        qfA[kk] = *(const bf16x8*)&Qb[(q0A + lr) * D_ + kk * 32 + lg * 8];
        qfB[kk] = *(const bf16x8*)&Qb[(q0B + lr) * D_ + kk * 32 + lg * 8];
    }

    bf16x8 ones;
#pragma unroll
    for (int e = 0; e < 8; ++e) ones[e] = (bf16_t)1.0f;

    f32x4 oA[4] = {}, oB[4] = {};
    f32x4 lA = {}, lB = {};

    int cur = 0;
    stageK(0, 0);
    stageV(0, 0);
    __syncthreads();

    for (int tkv = 0; tkv <= qtB; ++tkv) {
        const int kv0 = tkv * 64;
        if (tkv < qtB) { stageK(cur ^ 1, kv0 + 64); stageV(cur ^ 1, kv0 + 64); }

        auto process = [&](int q0, const bf16x8* qf, f32x4* o, f32x4& accl, bf16_t* Pw) {
            f32x4 sc[4] = {};
            __builtin_amdgcn_s_setprio(1);
#pragma unroll
            for (int nj = 0; nj < 4; ++nj) {
                if (kv0 + nj * 16 <= q0 + 15) {
                    const int krow = nj * 16 + lr;
#pragma unroll
                    for (int kk = 0; kk < 2; ++kk) {
                        bf16x8 kfr = *(const bf16x8*)&Ks[cur][krow * 64 + (((kk * 4 + lg) ^ (krow & 7)) * 8)];
                        sc[nj] = __builtin_amdgcn_mfma_f32_16x16x32_bf16(qf[kk], kfr, sc[nj], 0, 0, 0);
                    }
                }
            }
            __builtin_amdgcn_s_setprio(0);

            if (kv0 + 64 > q0) {
#pragma unroll
                for (int nj = 0; nj < 4; ++nj) {
                    const int col = kv0 + nj * 16 + lr;
#pragma unroll
                    for (int r = 0; r < 4; ++r) {
                        const int rowg = q0 + lg * 4 + r;
                        if (col > rowg) sc[nj][r] = -1e30f;
                    }
                }
            }

#pragma unroll
            for (int nj = 0; nj < 4; ++nj)
#pragma unroll
                for (int r = 0; r < 4; ++r)
                    Pw[psw(lg * 4 + r, nj * 16 + lr)] = (bf16_t)__builtin_amdgcn_exp2f(sc[nj][r]);
            asm volatile("s_waitcnt lgkmcnt(0)" ::: "memory");
            __builtin_amdgcn_sched_barrier(0);

            __builtin_amdgcn_s_setprio(1);
#pragma unroll
            for (int kk = 0; kk < 2; ++kk) {
                bf16x8 pa = *(const bf16x8*)&Pw[psw(lr, kk * 32 + lg * 8)];
                accl = __builtin_amdgcn_mfma_f32_16x16x32_bf16(pa, ones, accl, 0, 0, 0);
#pragma unroll
                for (int nd = 0; nd < 4; ++nd) {
                    const int vrow = nd * 16 + lr;
                    bf16x8 vf = *(const bf16x8*)&Vs[cur][vrow * 64 + (((kk * 4 + lg) ^ (vrow & 7)) * 8)];
                    o[nd] = __builtin_amdgcn_mfma_f32_16x16x32_bf16(pa, vf, o[nd], 0, 0, 0);
                }
            }
            __builtin_amdgcn_s_setprio(0);
        };

        process(q0B, qfB, oB, lB, &P_lds[w][0]);
        if (tkv <= qtA) process(q0A, qfA, oA, lA, &P_lds[w][0]);

        __syncthreads();
        cur ^= 1;
    }

    const int b = bh >> 4, h = bh & 15;
#pragma unroll
    for (int r = 0; r < 4; ++r) {
        const float rlA = 1.0f / lA[r];
        const float rlB = 1.0f / lB[r];
        const int rA = q0A + lg * 4 + r;
        const int rB = q0B + lg * 4 + r;
#pragma unroll
        for (int nd = 0; nd < 4; ++nd) {
            Og[((int64_t)(b * S_ + rA)) * E_ + h * D_ + nd * 16 + lr] = (bf16_t)(oA[nd][r] * rlA);
            Og[((int64_t)(b * S_ + rB)) * E_ + h * D_ + nd * 16 + lr] = (bf16_t)(oB[nd][r] * rlB);
        }
    }
}

// ---------------- launch ----------------
extern "C" void kernel_launch(void* const* d_in, const int* in_sizes, int n_in,
                              void* d_out, int out_size, void* d_ws, size_t ws_size,
                              hipStream_t stream) {
    const float* x    = (const float*)d_in[0];
    const float* Wa_w = (const float*)d_in[1];
    const float* Wa_b = (const float*)d_in[2];
    const float* Wo_w = (const float*)d_in[3];
    const float* Wo_b = (const float*)d_in[4];
    float* out = (float*)d_out;

    const size_t M = (size_t)B_ * S_;       // 8192
    char* ws = (char*)d_ws;
    bf16_t* xb  = (bf16_t*)ws; ws += M * E_ * 2;
    bf16_t* wab = (bf16_t*)ws; ws += (size_t)3 * E_ * E_ * 2;
    bf16_t* wob = (bf16_t*)ws; ws += (size_t)E_ * E_ * 2;
    bf16_t* Qg  = (bf16_t*)ws; ws += M * E_ * 2;
    bf16_t* Kg  = (bf16_t*)ws; ws += M * E_ * 2;
    bf16_t* Vtg = (bf16_t*)ws; ws += M * E_ * 2;
    bf16_t* Og  = (bf16_t*)ws; ws += M * E_ * 2;

    // single fused conversion launch (x, Wa_w, Wo_w)
    cvt_all<<<2048, 256, 0, stream>>>(x, Wa_w, Wo_w, xb, wab, wob);

    // QKV projection: paired tiles -> 768 blocks = exactly 1 round at 3/CU
    gemm_qkv<<<768, 256, 0, stream>>>(xb, wab, Wa_b, Qg, Kg, Vtg);

    // causal attention: pairs {i,31-i}, staged K/V, 1024 blocks, 4/CU
    attn_causal<<<B_ * H_ * 16, 256, 0, stream>>>(Qg, Kg, Vtg, Og);

    // output projection: barrier-free wave-private GEMM, 512 blocks = 2/CU exact
    gemm_proj<<<512, 256, 0, stream>>>(Og, wob, Wo_b, out);
}

// Round 16
// 173.655 us; speedup vs baseline: 1.0217x; 1.0217x over previous
//
#include <hip/hip_runtime.h>
#include <hip/hip_bf16.h>
#include <cstdint>

typedef __bf16 bf16_t;
typedef __attribute__((ext_vector_type(8))) __bf16 bf16x8;
typedef __attribute__((ext_vector_type(4))) __bf16 bf16x4;
typedef __attribute__((ext_vector_type(4))) float f32x4;

#define B_ 4
#define S_ 2048
#define E_ 1024
#define H_ 16
#define D_ 64

// Q pre-scale: (1/sqrt(D)) * log2(e) so softmax exp becomes a bare v_exp_f32 (2^x)
#define QSCALE 0.18033688011112042f

// ---------------- fused f32 -> bf16 conversion (single launch, 3 segments) --------
__global__ void cvt_all(const float* __restrict__ x, const float* __restrict__ wa,
                        const float* __restrict__ wo,
                        bf16_t* __restrict__ xb, bf16_t* __restrict__ wab,
                        bf16_t* __restrict__ wob) {
    constexpr int N1 = (B_ * S_ * E_) / 4;
    constexpr int N2 = (3 * E_ * E_) / 4;
    constexpr int N3 = (E_ * E_) / 4;
    int i = blockIdx.x * blockDim.x + threadIdx.x;
    int stride = gridDim.x * blockDim.x;
    for (; i < N1 + N2 + N3; i += stride) {
        const float* src; bf16_t* dst; int k;
        if (i < N1) { src = x; dst = xb; k = i; }
        else if (i < N1 + N2) { src = wa; dst = wab; k = i - N1; }
        else { src = wo; dst = wob; k = i - N1 - N2; }
        f32x4 v = reinterpret_cast<const f32x4*>(src)[k];
        bf16x4 o;
        o.x = (bf16_t)v.x; o.y = (bf16_t)v.y; o.z = (bf16_t)v.z; o.w = (bf16_t)v.w;
        reinterpret_cast<bf16x4*>(dst)[k] = o;
    }
}

// ---------------- async global->LDS helper ----------------
__device__ __forceinline__ void gload_lds16(const bf16_t* g, bf16_t* l) {
    __builtin_amdgcn_global_load_lds((const __attribute__((address_space(1))) void*)g,
                                     (__attribute__((address_space(3))) void*)l, 16, 0, 0);
}

__device__ __forceinline__ void wait_vm4() { asm volatile("s_waitcnt vmcnt(4)" ::: "memory"); }
__device__ __forceinline__ void wait_vm0() { asm volatile("s_waitcnt vmcnt(0)" ::: "memory"); }

// shared helpers for both GEMM kernels
__device__ __forceinline__ int fragOffG(int row, int kc) {
    const int line = row >> 1;
    const int ch = ((row & 1) << 2) | kc;
    return line * 64 + ((ch ^ (line & 7)) << 3);
}

// ---------------- paired-tile deep-pipelined bf16 GEMM (QKV) ----------------
// Each block computes TWO 128x128 output tiles (mt0, mt0+4) sharing one nt / B
// panel; 3-buffer counted-vmcnt ring crosses the tile boundary (no drain between
// tiles; tile-1 epilogue overlaps tile-2 staging). Grid 768 = exactly 1 round at
// 3/CU. Swizzled LDS (conflict-free), full-line epilogue.
__launch_bounds__(256, 3)
__global__ void gemm_qkv(const bf16_t* __restrict__ A, const bf16_t* __restrict__ Bm,
                         const float* __restrict__ bias,
                         bf16_t* __restrict__ Qg, bf16_t* __restrict__ Kg,
                         bf16_t* __restrict__ Vtg) {
    constexpr int K = 1024, BK = 32;
    constexpr int BM = 128, BN = 128;
    __shared__ __align__(16) bf16_t As[3][BM * BK];
    __shared__ __align__(16) bf16_t Bs[3][BN * BK];

    constexpr int NG = 12;
    const int xcd = blockIdx.x & 7;
    const int u = blockIdx.x >> 3;
    const int grp = 4 * NG;
    const int g = u / grp, r2 = u % grp;
    const int ntl = r2 >> 2, q = r2 & 3;
    const int mt0 = xcd * 8 + q;
    const int nt = g * NG + ntl;
    const int m0a = mt0 * BM, m0b = (mt0 + 4) * BM, n0 = nt * BN;

    const int t = threadIdx.x;
    const int lane = t & 63;
    const int wid = t >> 6;
    const int wr = wid >> 1, wc = wid & 1;
    const int lr = lane & 15, lg = lane >> 4;

    auto mkSrc = [&](const bf16_t* base, int c, int row0) {
        const int line = c >> 3, chg = (c & 7) ^ (line & 7);
        return base + (int64_t)(row0 + 2 * line + (chg >> 2)) * K + (chg & 3) * 8;
    };
    const bf16_t* aSrcA0 = mkSrc(A, t, m0a);
    const bf16_t* aSrcA1 = mkSrc(A, t + 256, m0a);
    const bf16_t* aSrcB0 = mkSrc(A, t, m0b);
    const bf16_t* aSrcB1 = mkSrc(A, t + 256, m0b);
    const bf16_t* bSrc0 = mkSrc(Bm, t, n0);
    const bf16_t* bSrc1 = mkSrc(Bm, t + 256, n0);

    auto stageT = [&](int v, int buf) {
        const int kt = v & 31;
        const bf16_t* a0 = (v < 32) ? aSrcA0 : aSrcB0;
        const bf16_t* a1 = (v < 32) ? aSrcA1 : aSrcB1;
        gload_lds16(a0 + kt * BK, &As[buf][t * 8]);
        gload_lds16(a1 + kt * BK, &As[buf][(t + 256) * 8]);
        gload_lds16(bSrc0 + kt * BK, &Bs[buf][t * 8]);
        gload_lds16(bSrc1 + kt * BK, &Bs[buf][(t + 256) * 8]);
    };

    f32x4 acc[4][4] = {};

    float bv[4];
#pragma unroll
    for (int j = 0; j < 4; ++j) bv[j] = bias[n0 + wc * 64 + j * 16 + lr];

    auto epi = [&](int m0) {
        const int which = n0 >> 10;
        const int h = (((n0 & 1023) + wc * 64) >> 6);
#pragma unroll
        for (int i = 0; i < 4; ++i) {
#pragma unroll
            for (int r = 0; r < 4; ++r) {
                const int m = m0 + wr * 64 + i * 16 + lg * 4 + r;
                const int b = m >> 11, si = m & (S_ - 1);
                if (which == 0) {
                    bf16_t* p = &Qg[(((int64_t)(b * H_ + h)) * S_ + si) * D_ + lr];
#pragma unroll
                    for (int j = 0; j < 4; ++j)
                        p[j * 16] = (bf16_t)((acc[i][j][r] + bv[j]) * QSCALE);
                } else if (which == 1) {
                    bf16_t* p = &Kg[(((int64_t)(b * H_ + h)) * S_ + si) * D_ + lr];
#pragma unroll
                    for (int j = 0; j < 4; ++j)
                        p[j * 16] = (bf16_t)(acc[i][j][r] + bv[j]);
                } else {
                    bf16_t* p = &Vtg[(((int64_t)(b * H_ + h)) * D_ + lr) * S_ + si];
#pragma unroll
                    for (int j = 0; j < 4; ++j)
                        p[(int64_t)(j * 16) * S_] = (bf16_t)(acc[i][j][r] + bv[j]);
                }
            }
        }
    };

    auto body = [&](int bufc) {
        bf16x8 bfr[4], afr[4];
#pragma unroll
        for (int j = 0; j < 4; ++j)
            bfr[j] = *(const bf16x8*)&Bs[bufc][fragOffG(wc * 64 + j * 16 + lr, lg)];
#pragma unroll
        for (int i = 0; i < 4; ++i)
            afr[i] = *(const bf16x8*)&As[bufc][fragOffG(wr * 64 + i * 16 + lr, lg)];
#pragma unroll
        for (int i = 0; i < 4; ++i)
#pragma unroll
            for (int j = 0; j < 4; ++j)
                acc[i][j] = __builtin_amdgcn_mfma_f32_16x16x32_bf16(afr[i], bfr[j], acc[i][j], 0, 0, 0);
    };

    stageT(0, 0);
    stageT(1, 1);

    int bufc = 0, bufs = 2;
    for (int v = 0; v < 32; ++v) {
        wait_vm4();
        __builtin_amdgcn_s_barrier();
        __builtin_amdgcn_sched_barrier(0);
        stageT(v + 2, bufs);            // crosses into tile b — no drain
        body(bufc);
        bufc = (bufc == 2) ? 0 : bufc + 1;
        bufs = (bufs == 2) ? 0 : bufs + 1;
    }
    epi(m0a);
#pragma unroll
    for (int i = 0; i < 4; ++i)
#pragma unroll
        for (int j = 0; j < 4; ++j)
            acc[i][j] = f32x4{0.f, 0.f, 0.f, 0.f};

    for (int v = 32; v < 64; ++v) {
        if (v < 63) wait_vm4(); else wait_vm0();
        __builtin_amdgcn_s_barrier();
        __builtin_amdgcn_sched_barrier(0);
        if (v + 2 < 64) stageT(v + 2, bufs);
        body(bufc);
        bufc = (bufc == 2) ? 0 : bufc + 1;
        bufs = (bufs == 2) ? 0 : bufs + 1;
    }
    epi(m0b);
}

// ---------------- single-tile deep-pipelined GEMM (output projection, r11 proven) --
// Tile 128x128, 512 blocks = balanced 2/CU; hierarchical XCD mapping NG=8.
__launch_bounds__(256, 3)
__global__ void gemm_proj(const bf16_t* __restrict__ A, const bf16_t* __restrict__ Bm,
                          const float* __restrict__ bias, float* __restrict__ Outf) {
    constexpr int K = 1024, BK = 32, NKT = K / BK;
    constexpr int BM = 128, BN = 128, N = 1024, NG = 8;
    __shared__ __align__(16) bf16_t As[3][BM * BK];
    __shared__ __align__(16) bf16_t Bs[3][BN * BK];

    const int xcd = blockIdx.x & 7;
    const int u = blockIdx.x >> 3;
    const int grp = 8 * NG;
    const int g = u / grp, r2 = u % grp;
    const int ntl = r2 / 8, mtl = r2 & 7;
    const int mt = xcd * 8 + mtl;
    const int nt = g * NG + ntl;
    const int m0 = mt * BM, n0 = nt * BN;

    const int t = threadIdx.x;
    const int lane = t & 63;
    const int wid = t >> 6;
    const int wr = wid >> 1, wc = wid & 1;
    const int lr = lane & 15, lg = lane >> 4;

    auto mkSrc = [&](const bf16_t* base, int c, int row0) {
        const int line = c >> 3, chg = (c & 7) ^ (line & 7);
        return base + (int64_t)(row0 + 2 * line + (chg >> 2)) * K + (chg & 3) * 8;
    };
    const bf16_t* aSrc0 = mkSrc(A, t, m0);
    const bf16_t* aSrc1 = mkSrc(A, t + 256, m0);
    const bf16_t* bSrc0 = mkSrc(Bm, t, n0);
    const bf16_t* bSrc1 = mkSrc(Bm, t + 256, n0);

    auto stageT = [&](int kt, int buf) {
        gload_lds16(aSrc0 + kt * BK, &As[buf][t * 8]);
        gload_lds16(aSrc1 + kt * BK, &As[buf][(t + 256) * 8]);
        gload_lds16(bSrc0 + kt * BK, &Bs[buf][t * 8]);
        gload_lds16(bSrc1 + kt * BK, &Bs[buf][(t + 256) * 8]);
    };

    f32x4 acc[4][4] = {};

    stageT(0, 0);
    stageT(1, 1);

    int bufc = 0, bufs = 2;
    for (int kt = 0; kt < NKT; ++kt) {
        if (kt < NKT - 1) wait_vm4(); else wait_vm0();
        __builtin_amdgcn_s_barrier();
        __builtin_amdgcn_sched_barrier(0);

        if (kt + 2 < NKT) stageT(kt + 2, bufs);

        bf16x8 bfr[4], afr[4];
#pragma unroll
        for (int j = 0; j < 4; ++j)
            bfr[j] = *(const bf16x8*)&Bs[bufc][fragOffG(wc * 64 + j * 16 + lr, lg)];
#pragma unroll
        for (int i = 0; i < 4; ++i)
            afr[i] = *(const bf16x8*)&As[bufc][fragOffG(wr * 64 + i * 16 + lr, lg)];

#pragma unroll
        for (int i = 0; i < 4; ++i)
#pragma unroll
            for (int j = 0; j < 4; ++j)
                acc[i][j] = __builtin_amdgcn_mfma_f32_16x16x32_bf16(afr[i], bfr[j], acc[i][j], 0, 0, 0);

        bufc = (bufc == 2) ? 0 : bufc + 1;
        bufs = (bufs == 2) ? 0 : bufs + 1;
    }

    float bv[4];
#pragma unroll
    for (int j = 0; j < 4; ++j) bv[j] = bias[n0 + wc * 64 + j * 16 + lr];
#pragma unroll
    for (int i = 0; i < 4; ++i) {
#pragma unroll
        for (int r = 0; r < 4; ++r) {
            const int m = m0 + wr * 64 + i * 16 + lg * 4 + r;
            float* p = &Outf[(int64_t)m * N + n0 + wc * 64 + lr];
#pragma unroll
            for (int j = 0; j < 4; ++j)
                p[j * 16] = acc[i][j][r] + bv[j];
        }
    }
}

// ---------------- flash-style causal attention, work-balanced pairs (r11 proven) --
__launch_bounds__(256, 4)
__global__ void attn_causal(const bf16_t* __restrict__ Qg, const bf16_t* __restrict__ Kg,
                            const bf16_t* __restrict__ Vtg, bf16_t* __restrict__ Og) {
    __shared__ __align__(16) bf16_t Ks[2][64 * 64];   // 16 KiB
    __shared__ __align__(16) bf16_t Vs[2][64 * 64];   // 16 KiB
    __shared__ __align__(16) bf16_t P_lds[4][16 * 64]; // 8 KiB, swizzled

    const int bid = blockIdx.x;
    const int xcd = bid & 7, j = bid >> 3;
    const int bh = (j >> 4) * 8 + xcd;
    const int i = j & 15;
    const int qtA = i, qtB = 31 - i;

    const int t = threadIdx.x, lane = t & 63, w = t >> 6;
    const int lr = lane & 15, lg = lane >> 4;
    const int q0A = qtA * 64 + w * 16;
    const int q0B = qtB * 64 + w * 16;

    const bf16_t* Qb = Qg + (int64_t)bh * S_ * D_;
    const bf16_t* Kb = Kg + (int64_t)bh * S_ * D_;
    const bf16_t* Vb = Vtg + (int64_t)bh * D_ * S_;

    const int srow = t >> 3;
    const int scol_sw = (t & 7) ^ (srow & 7);

    auto stageK = [&](int buf, int kv0) {
        const bf16_t* base = Kb + (kv0 + srow) * D_ + scol_sw * 8;
        gload_lds16(base, &Ks[buf][t * 8]);
        gload_lds16(base + 32 * D_, &Ks[buf][t * 8 + 2048]);
    };
    auto stageV = [&](int buf, int kv0) {
        const bf16_t* base = Vb + srow * S_ + kv0 + scol_sw * 8;
        gload_lds16(base, &Vs[buf][t * 8]);
        gload_lds16(base + 32 * S_, &Vs[buf][t * 8 + 2048]);
    };

    auto psw = [](int row, int col) {
        return row * 64 + ((((col >> 3) ^ (row & 7)) << 3) | (col & 7));
    };

    bf16x8 qfA[2], qfB[2];
#pragma unroll
    for (int kk = 0; kk < 2; ++kk) {
        qfA[kk] = *(const bf16x8*)&Qb[(q0A + lr) * D_ + kk * 32 + lg * 8];
        qfB[kk] = *(const bf16x8*)&Qb[(q0B + lr) * D_ + kk * 32 + lg * 8];
    }

    bf16x8 ones;
#pragma unroll
    for (int e = 0; e < 8; ++e) ones[e] = (bf16_t)1.0f;

    f32x4 oA[4] = {}, oB[4] = {};
    f32x4 lA = {}, lB = {};

    int cur = 0;
    stageK(0, 0);
    stageV(0, 0);
    __syncthreads();

    for (int tkv = 0; tkv <= qtB; ++tkv) {
        const int kv0 = tkv * 64;
        if (tkv < qtB) { stageK(cur ^ 1, kv0 + 64); stageV(cur ^ 1, kv0 + 64); }

        auto process = [&](int q0, const bf16x8* qf, f32x4* o, f32x4& accl, bf16_t* Pw) {
            f32x4 sc[4] = {};
            __builtin_amdgcn_s_setprio(1);
#pragma unroll
            for (int nj = 0; nj < 4; ++nj) {
                if (kv0 + nj * 16 <= q0 + 15) {
                    const int krow = nj * 16 + lr;
#pragma unroll
                    for (int kk = 0; kk < 2; ++kk) {
                        bf16x8 kfr = *(const bf16x8*)&Ks[cur][krow * 64 + (((kk * 4 + lg) ^ (krow & 7)) * 8)];
                        sc[nj] = __builtin_amdgcn_mfma_f32_16x16x32_bf16(qf[kk], kfr, sc[nj], 0, 0, 0);
                    }
                }
            }
            __builtin_amdgcn_s_setprio(0);

            if (kv0 + 64 > q0) {
#pragma unroll
                for (int nj = 0; nj < 4; ++nj) {
                    const int col = kv0 + nj * 16 + lr;
#pragma unroll
                    for (int r = 0; r < 4; ++r) {
                        const int rowg = q0 + lg * 4 + r;
                        if (col > rowg) sc[nj][r] = -1e30f;
                    }
                }
            }

#pragma unroll
            for (int nj = 0; nj < 4; ++nj)
#pragma unroll
                for (int r = 0; r < 4; ++r)
                    Pw[psw(lg * 4 + r, nj * 16 + lr)] = (bf16_t)__builtin_amdgcn_exp2f(sc[nj][r]);
            asm volatile("s_waitcnt lgkmcnt(0)" ::: "memory");
            __builtin_amdgcn_sched_barrier(0);

            __builtin_amdgcn_s_setprio(1);
#pragma unroll
            for (int kk = 0; kk < 2; ++kk) {
                bf16x8 pa = *(const bf16x8*)&Pw[psw(lr, kk * 32 + lg * 8)];
                accl = __builtin_amdgcn_mfma_f32_16x16x32_bf16(pa, ones, accl, 0, 0, 0);
#pragma unroll
                for (int nd = 0; nd < 4; ++nd) {
                    const int vrow = nd * 16 + lr;
                    bf16x8 vf = *(const bf16x8*)&Vs[cur][vrow * 64 + (((kk * 4 + lg) ^ (vrow & 7)) * 8)];
                    o[nd] = __builtin_amdgcn_mfma_f32_16x16x32_bf16(pa, vf, o[nd], 0, 0, 0);
                }
            }
            __builtin_amdgcn_s_setprio(0);
        };

        process(q0B, qfB, oB, lB, &P_lds[w][0]);
        if (tkv <= qtA) process(q0A, qfA, oA, lA, &P_lds[w][0]);

        __syncthreads();
        cur ^= 1;
    }

    const int b = bh >> 4, h = bh & 15;
#pragma unroll
    for (int r = 0; r < 4; ++r) {
        const float rlA = 1.0f / lA[r];
        const float rlB = 1.0f / lB[r];
        const int rA = q0A + lg * 4 + r;
        const int rB = q0B + lg * 4 + r;
#pragma unroll
        for (int nd = 0; nd < 4; ++nd) {
            Og[((int64_t)(b * S_ + rA)) * E_ + h * D_ + nd * 16 + lr] = (bf16_t)(oA[nd][r] * rlA);
            Og[((int64_t)(b * S_ + rB)) * E_ + h * D_ + nd * 16 + lr] = (bf16_t)(oB[nd][r] * rlB);
        }
    }
}

// ---------------- launch ----------------
extern "C" void kernel_launch(void* const* d_in, const int* in_sizes, int n_in,
                              void* d_out, int out_size, void* d_ws, size_t ws_size,
                              hipStream_t stream) {
    const float* x    = (const float*)d_in[0];
    const float* Wa_w = (const float*)d_in[1];
    const float* Wa_b = (const float*)d_in[2];
    const float* Wo_w = (const float*)d_in[3];
    const float* Wo_b = (const float*)d_in[4];
    float* out = (float*)d_out;

    const size_t M = (size_t)B_ * S_;       // 8192
    char* ws = (char*)d_ws;
    bf16_t* xb  = (bf16_t*)ws; ws += M * E_ * 2;
    bf16_t* wab = (bf16_t*)ws; ws += (size_t)3 * E_ * E_ * 2;
    bf16_t* wob = (bf16_t*)ws; ws += (size_t)E_ * E_ * 2;
    bf16_t* Qg  = (bf16_t*)ws; ws += M * E_ * 2;
    bf16_t* Kg  = (bf16_t*)ws; ws += M * E_ * 2;
    bf16_t* Vtg = (bf16_t*)ws; ws += M * E_ * 2;
    bf16_t* Og  = (bf16_t*)ws; ws += M * E_ * 2;

    // single fused conversion launch (x, Wa_w, Wo_w)
    cvt_all<<<2048, 256, 0, stream>>>(x, Wa_w, Wo_w, xb, wab, wob);

    // QKV projection: paired tiles -> 768 blocks = exactly 1 round at 3/CU
    gemm_qkv<<<768, 256, 0, stream>>>(xb, wab, Wa_b, Qg, Kg, Vtg);

    // causal attention: pairs {i,31-i}, staged K/V, 1024 blocks, 4/CU
    attn_causal<<<B_ * H_ * 16, 256, 0, stream>>>(Qg, Kg, Vtg, Og);

    // output projection: single tiles -> 512 blocks = 2/CU (r11 proven)
    gemm_proj<<<512, 256, 0, stream>>>(Og, wob, Wo_b, out);
}